// Round 1
// baseline (538.016 us; speedup 1.0000x reference)
//
#include <hip/hip_runtime.h>

#define N_NODES  50000
#define N_EDGES  600000
#define N_GRAPHS 512
#define DIM      128
#define N_FEAT   78
#define N_LAYERS 4
#define BN_EPS   1e-5f
#define SLOT_CAP 64
#define LDA      136

#define EDGE_BLOCKS ((N_EDGES + 255) / 256)   // 2344
#define ZERO_BLOCKS 512                       // zero 2 MB of gsum+gssq (1 MB each)
#define BG_BLOCKS (EDGE_BLOCKS + 1 + ZERO_BLOCKS)

typedef __attribute__((ext_vector_type(8))) _Float16 f16x8;
typedef __attribute__((ext_vector_type(4))) float f32x4;

static __device__ __forceinline__ short f2h(float f) {
    _Float16 h = (_Float16)f;
    union { _Float16 h; short s; } u; u.h = h;
    return u.s;
}
static __device__ __forceinline__ float h2f(ushort s) {
    union { ushort s; _Float16 h; } u; u.s = s;
    return (float)u.h;
}

// ---------------- graph build: ushort slotted adjacency + gcount + affine + zeroing ----

__global__ __launch_bounds__(256) void build_graph(const int* __restrict__ src,
                                                   const int* __restrict__ dst,
                                                   const int* __restrict__ batch,
                                                   int* __restrict__ cnt,
                                                   ushort* __restrict__ slot,
                                                   int* __restrict__ gcnt,
                                                   float* __restrict__ aff,
                                                   float* __restrict__ gsum,
                                                   float* __restrict__ gssq) {
    int b = blockIdx.x;
    int tid = threadIdx.x;
    if (b < EDGE_BLOCKS) {
        int e = b * 256 + tid;
        if (e < N_EDGES) {
            int d = dst[e];
            int p = atomicAdd(&cnt[d], 1);
            if (p < SLOT_CAP) slot[d * SLOT_CAP + p] = (ushort)src[e];
        }
        if (e < N_NODES) atomicAdd(&gcnt[batch[e]], 1);
    } else if (b == EDGE_BLOCKS) {
        if (tid < 128) {
            aff[tid] = 1.0f;
            aff[128 + tid] = 0.0f;
        }
    } else {
        int zb = b - EDGE_BLOCKS - 1;      // 0..511
        float4 z = make_float4(0.f, 0.f, 0.f, 0.f);
        float* base = (zb < 256) ? gsum : gssq;
        int off = (zb & 255) * 1024 + tid * 4;   // 1024 floats per block
        *(float4*)&base[off] = z;
    }
}

// ---------------- weight pre-transpose: W[K][128] fp32 -> Wt[n][k] fp16 ----------------

__global__ __launch_bounds__(256) void transpose_weights(const float* __restrict__ ini_w1,
                                                         const float* __restrict__ ini_w2,
                                                         const float* __restrict__ gw1,
                                                         const float* __restrict__ gw2,
                                                         short* __restrict__ wt) {
    int gid = blockIdx.x * 256 + threadIdx.x;
    if (gid >= 10 * 16384) return;
    int m = gid >> 14;
    int idx = gid & 16383;
    int n = idx >> 7;
    int k = idx & 127;
    const float* src;
    int K = 128;
    if (m == 0) { src = ini_w1; K = N_FEAT; }
    else if (m == 1) src = ini_w2;
    else if (m < 6) src = gw1 + (m - 2) * 16384;
    else src = gw2 + (m - 6) * 16384;
    float v = (k < K) ? src[k * 128 + n] : 0.f;
    wt[m * 16384 + n * 128 + k] = f2h(v);
}

// ---------------- initial 2-layer MLP from fp32 features ----------------
// C = relu(A@W1+b1)@W2+b2   (no relu2, no stats)

__global__ __launch_bounds__(256) void gemm_mlp_ini(const float* __restrict__ A,
                                                    const short* __restrict__ Wt1,
                                                    const float* __restrict__ b1,
                                                    const short* __restrict__ Wt2,
                                                    const float* __restrict__ b2,
                                                    ushort* __restrict__ C) {
    __shared__ short As[64 * LDA];
    __shared__ short Ws[128 * LDA];
    int tid = threadIdx.x;
    int row0 = blockIdx.x * 64;

    #pragma unroll
    for (int j = 0; j < 8; ++j) {
        int lin = tid + j * 256;
        int n = lin >> 4;
        int kc = lin & 15;
        *(uint4*)&Ws[n * LDA + kc * 8] = *(const uint4*)&Wt1[n * 128 + kc * 8];
    }
    #pragma unroll
    for (int j = 0; j < 32; ++j) {
        int lin = tid + j * 256;
        int r = lin >> 7;
        int k = lin & 127;
        int gr = row0 + r;
        float v = 0.f;
        if (gr < N_NODES && k < N_FEAT) v = A[gr * N_FEAT + k];
        As[r * LDA + k] = f2h(v);
    }
    __syncthreads();

    int wave = tid >> 6;
    int lane = tid & 63;
    int rw = wave >> 1;
    int cw = wave & 1;
    int lm = lane & 15;
    int quad = lane >> 4;

    f32x4 acc[2][4];
    #pragma unroll
    for (int mt = 0; mt < 2; ++mt)
        #pragma unroll
        for (int nt = 0; nt < 4; ++nt)
            acc[mt][nt] = (f32x4){0.f, 0.f, 0.f, 0.f};

    #pragma unroll
    for (int ks = 0; ks < 4; ++ks) {
        int kb = ks * 32 + quad * 8;
        f16x8 a0 = *(const f16x8*)&As[(rw * 32 + lm) * LDA + kb];
        f16x8 a1 = *(const f16x8*)&As[(rw * 32 + 16 + lm) * LDA + kb];
        #pragma unroll
        for (int nt = 0; nt < 4; ++nt) {
            f16x8 b = *(const f16x8*)&Ws[(cw * 64 + nt * 16 + lm) * LDA + kb];
            acc[0][nt] = __builtin_amdgcn_mfma_f32_16x16x32_f16(a0, b, acc[0][nt], 0, 0, 0);
            acc[1][nt] = __builtin_amdgcn_mfma_f32_16x16x32_f16(a1, b, acc[1][nt], 0, 0, 0);
        }
    }
    __syncthreads();

    ushort* Cs = (ushort*)As;
    #pragma unroll
    for (int nt = 0; nt < 4; ++nt) {
        int col = cw * 64 + nt * 16 + lm;
        float bv = b1[col];
        #pragma unroll
        for (int mt = 0; mt < 2; ++mt) {
            #pragma unroll
            for (int r = 0; r < 4; ++r) {
                int row = rw * 32 + mt * 16 + quad * 4 + r;
                Cs[row * LDA + col] = (ushort)f2h(fmaxf(acc[mt][nt][r] + bv, 0.f));
            }
        }
    }
    #pragma unroll
    for (int j = 0; j < 8; ++j) {
        int lin = tid + j * 256;
        int n = lin >> 4;
        int kc = lin & 15;
        *(uint4*)&Ws[n * LDA + kc * 8] = *(const uint4*)&Wt2[n * 128 + kc * 8];
    }
    __syncthreads();

    #pragma unroll
    for (int mt = 0; mt < 2; ++mt)
        #pragma unroll
        for (int nt = 0; nt < 4; ++nt)
            acc[mt][nt] = (f32x4){0.f, 0.f, 0.f, 0.f};
    #pragma unroll
    for (int ks = 0; ks < 4; ++ks) {
        int kb = ks * 32 + quad * 8;
        f16x8 a0 = *(const f16x8*)&As[(rw * 32 + lm) * LDA + kb];
        f16x8 a1 = *(const f16x8*)&As[(rw * 32 + 16 + lm) * LDA + kb];
        #pragma unroll
        for (int nt = 0; nt < 4; ++nt) {
            f16x8 b = *(const f16x8*)&Ws[(cw * 64 + nt * 16 + lm) * LDA + kb];
            acc[0][nt] = __builtin_amdgcn_mfma_f32_16x16x32_f16(a0, b, acc[0][nt], 0, 0, 0);
            acc[1][nt] = __builtin_amdgcn_mfma_f32_16x16x32_f16(a1, b, acc[1][nt], 0, 0, 0);
        }
    }
    __syncthreads();

    #pragma unroll
    for (int nt = 0; nt < 4; ++nt) {
        int col = cw * 64 + nt * 16 + lm;
        float bv = b2[col];
        #pragma unroll
        for (int mt = 0; mt < 2; ++mt) {
            #pragma unroll
            for (int r = 0; r < 4; ++r) {
                int row = rw * 32 + mt * 16 + quad * 4 + r;
                Cs[row * LDA + col] = (ushort)f2h(acc[mt][nt][r] + bv);
            }
        }
    }
    __syncthreads();
    #pragma unroll
    for (int j = 0; j < 4; ++j) {
        int lin = tid + j * 256;
        int r = lin >> 4;
        int kc = lin & 15;
        int gr = row0 + r;
        if (gr < N_NODES)
            *(uint4*)&C[gr * 128 + kc * 8] = *(const uint4*)&Cs[r * LDA + kc * 8];
    }
}

// ---------------- fused GIN layer: aggregation (+folded BN affine) -> 2-layer MLP ----
// As[r] = s ⊙ (Z[r] + Σ_{j->r} Z[j]) + (1+deg[r]) ⊙ t, built directly in LDS,
// then C = relu(relu(As@W1+b1)@W2+b2), with per-graph Σ and Σ² side outputs.

__global__ __launch_bounds__(256) void gin_layer(const ushort* __restrict__ Z,
                                                 const int* __restrict__ cnt,
                                                 const ushort* __restrict__ slot,
                                                 const float* __restrict__ aff,
                                                 const short* __restrict__ Wt1,
                                                 const float* __restrict__ b1,
                                                 const short* __restrict__ Wt2,
                                                 const float* __restrict__ b2,
                                                 ushort* __restrict__ C,
                                                 const int* __restrict__ batch,
                                                 float* __restrict__ gsum,
                                                 float* __restrict__ gssq) {
    __shared__ short As[64 * LDA];
    __shared__ short Ws[128 * LDA];
    __shared__ int sb[64];
    int tid = threadIdx.x;
    int row0 = blockIdx.x * 64;

    // W1 -> LDS (independent of aggregation; issue first)
    #pragma unroll
    for (int j = 0; j < 8; ++j) {
        int lin = tid + j * 256;
        int n = lin >> 4;
        int kc = lin & 15;
        *(uint4*)&Ws[n * LDA + kc * 8] = *(const uint4*)&Wt1[n * 128 + kc * 8];
    }
    if (tid < 64) {
        int n = row0 + tid;
        sb[tid] = (n < N_NODES) ? batch[n] : -1;
    }

    // ---- aggregation phase: 16 lanes per node, 16 nodes per pass, 4 passes ----
    int lane = tid & 15;
    int nsub = tid >> 4;
    float sc[8], tc[8];
    #pragma unroll
    for (int j = 0; j < 8; ++j) {
        sc[j] = aff[lane * 8 + j];
        tc[j] = aff[128 + lane * 8 + j];
    }
    const uint4* z4 = (const uint4*)Z;
    union U { uint4 u; _Float16 h[8]; };
    union I { uint4 u; ushort s[8]; };

    #pragma unroll
    for (int pass = 0; pass < 4; ++pass) {
        int r = pass * 16 + nsub;
        int node = row0 + r;
        float v[8];
        float dsc = 1.0f;
        if (node < N_NODES) {
            U zu; zu.u = z4[node * 16 + lane];
            #pragma unroll
            for (int j = 0; j < 8; ++j) v[j] = (float)zu.h[j];
            int dtrue = cnt[node];
            int d = min(dtrue, SLOT_CAP);
            const ushort* sl = slot + node * SLOT_CAP;
            int e = 0;
            for (; e + 8 <= d; e += 8) {
                I si; si.u = *(const uint4*)&sl[e];
                U u[8];
                #pragma unroll
                for (int q = 0; q < 8; ++q) u[q].u = z4[(int)si.s[q] * 16 + lane];
                #pragma unroll
                for (int j = 0; j < 8; ++j) {
                    float a = ((float)u[0].h[j] + (float)u[1].h[j]) +
                              ((float)u[2].h[j] + (float)u[3].h[j]);
                    float b = ((float)u[4].h[j] + (float)u[5].h[j]) +
                              ((float)u[6].h[j] + (float)u[7].h[j]);
                    v[j] += a + b;
                }
            }
            if (e + 4 <= d) {
                int s0 = sl[e], s1 = sl[e + 1], s2 = sl[e + 2], s3 = sl[e + 3];
                U u0, u1, u2, u3;
                u0.u = z4[s0 * 16 + lane];
                u1.u = z4[s1 * 16 + lane];
                u2.u = z4[s2 * 16 + lane];
                u3.u = z4[s3 * 16 + lane];
                #pragma unroll
                for (int j = 0; j < 8; ++j)
                    v[j] += ((float)u0.h[j] + (float)u1.h[j]) +
                            ((float)u2.h[j] + (float)u3.h[j]);
                e += 4;
            }
            for (; e < d; ++e) {
                U u; u.u = z4[(int)sl[e] * 16 + lane];
                #pragma unroll
                for (int j = 0; j < 8; ++j) v[j] += (float)u.h[j];
            }
            dsc = 1.0f + (float)dtrue;
        } else {
            #pragma unroll
            for (int j = 0; j < 8; ++j) v[j] = 0.f;
        }
        #pragma unroll
        for (int j = 0; j < 8; ++j)
            As[r * LDA + lane * 8 + j] = f2h(sc[j] * v[j] + dsc * tc[j]);
    }
    __syncthreads();

    // ---- GEMM 1 ----
    int wave = tid >> 6;
    int wlane = tid & 63;
    int rw = wave >> 1;
    int cw = wave & 1;
    int lm = wlane & 15;
    int quad = wlane >> 4;

    f32x4 acc[2][4];
    #pragma unroll
    for (int mt = 0; mt < 2; ++mt)
        #pragma unroll
        for (int nt = 0; nt < 4; ++nt)
            acc[mt][nt] = (f32x4){0.f, 0.f, 0.f, 0.f};

    #pragma unroll
    for (int ks = 0; ks < 4; ++ks) {
        int kb = ks * 32 + quad * 8;
        f16x8 a0 = *(const f16x8*)&As[(rw * 32 + lm) * LDA + kb];
        f16x8 a1 = *(const f16x8*)&As[(rw * 32 + 16 + lm) * LDA + kb];
        #pragma unroll
        for (int nt = 0; nt < 4; ++nt) {
            f16x8 b = *(const f16x8*)&Ws[(cw * 64 + nt * 16 + lm) * LDA + kb];
            acc[0][nt] = __builtin_amdgcn_mfma_f32_16x16x32_f16(a0, b, acc[0][nt], 0, 0, 0);
            acc[1][nt] = __builtin_amdgcn_mfma_f32_16x16x32_f16(a1, b, acc[1][nt], 0, 0, 0);
        }
    }
    __syncthreads();

    ushort* Cs = (ushort*)As;
    #pragma unroll
    for (int nt = 0; nt < 4; ++nt) {
        int col = cw * 64 + nt * 16 + lm;
        float bv = b1[col];
        #pragma unroll
        for (int mt = 0; mt < 2; ++mt) {
            #pragma unroll
            for (int r = 0; r < 4; ++r) {
                int row = rw * 32 + mt * 16 + quad * 4 + r;
                Cs[row * LDA + col] = (ushort)f2h(fmaxf(acc[mt][nt][r] + bv, 0.f));
            }
        }
    }
    #pragma unroll
    for (int j = 0; j < 8; ++j) {
        int lin = tid + j * 256;
        int n = lin >> 4;
        int kc = lin & 15;
        *(uint4*)&Ws[n * LDA + kc * 8] = *(const uint4*)&Wt2[n * 128 + kc * 8];
    }
    __syncthreads();

    // ---- GEMM 2 ----
    #pragma unroll
    for (int mt = 0; mt < 2; ++mt)
        #pragma unroll
        for (int nt = 0; nt < 4; ++nt)
            acc[mt][nt] = (f32x4){0.f, 0.f, 0.f, 0.f};
    #pragma unroll
    for (int ks = 0; ks < 4; ++ks) {
        int kb = ks * 32 + quad * 8;
        f16x8 a0 = *(const f16x8*)&As[(rw * 32 + lm) * LDA + kb];
        f16x8 a1 = *(const f16x8*)&As[(rw * 32 + 16 + lm) * LDA + kb];
        #pragma unroll
        for (int nt = 0; nt < 4; ++nt) {
            f16x8 b = *(const f16x8*)&Ws[(cw * 64 + nt * 16 + lm) * LDA + kb];
            acc[0][nt] = __builtin_amdgcn_mfma_f32_16x16x32_f16(a0, b, acc[0][nt], 0, 0, 0);
            acc[1][nt] = __builtin_amdgcn_mfma_f32_16x16x32_f16(a1, b, acc[1][nt], 0, 0, 0);
        }
    }
    __syncthreads();

    #pragma unroll
    for (int nt = 0; nt < 4; ++nt) {
        int col = cw * 64 + nt * 16 + lm;
        float bv = b2[col];
        #pragma unroll
        for (int mt = 0; mt < 2; ++mt) {
            #pragma unroll
            for (int r = 0; r < 4; ++r) {
                int row = rw * 32 + mt * 16 + quad * 4 + r;
                float o = fmaxf(acc[mt][nt][r] + bv, 0.f);   // relu2 always on
                Cs[row * LDA + col] = (ushort)f2h(o);
            }
        }
    }
    __syncthreads();
    #pragma unroll
    for (int j = 0; j < 4; ++j) {
        int lin = tid + j * 256;
        int r = lin >> 4;
        int kc = lin & 15;
        int gr = row0 + r;
        if (gr < N_NODES)
            *(uint4*)&C[gr * 128 + kc * 8] = *(const uint4*)&Cs[r * LDA + kc * 8];
    }
    // ---- per-graph stats (Σ, Σ²) ----
    {
        int c = tid & 127;
        int rbase = (tid >> 7) * 32;
        int curg = sb[rbase];
        float rs = 0.f, rss = 0.f;
        for (int r = rbase; r < rbase + 32; ++r) {
            int g = sb[r];
            if (g < 0) break;
            if (g != curg) {
                atomicAdd(&gsum[curg * 128 + c], rs);
                atomicAdd(&gssq[curg * 128 + c], rss);
                rs = 0.f; rss = 0.f; curg = g;
            }
            float v = h2f(Cs[r * LDA + c]);
            rs += v; rss += v * v;
        }
        if (curg >= 0) {
            atomicAdd(&gsum[curg * 128 + c], rs);
            atomicAdd(&gssq[curg * 128 + c], rss);
        }
    }
}

// ---------------- finalize: Σ_g gsum/gssq -> BN affine (s, t) ----------------

__global__ __launch_bounds__(512) void finalize_bn(const float* __restrict__ gsum,
                                                   const float* __restrict__ gssq,
                                                   const float* __restrict__ gamma,
                                                   const float* __restrict__ beta,
                                                   float* __restrict__ aff) {
    __shared__ float rs[512], rss[512];
    int t = threadIdx.x;
    int d = t & 127, grp = t >> 7;
    float s = 0.f, ss = 0.f;
    for (int g = grp; g < N_GRAPHS; g += 4) {
        s += gsum[g * 128 + d];
        ss += gssq[g * 128 + d];
    }
    rs[t] = s; rss[t] = ss;
    __syncthreads();
    if (t < 128) {
        s = rs[t] + rs[t + 128] + rs[t + 256] + rs[t + 384];
        ss = rss[t] + rss[t + 128] + rss[t + 256] + rss[t + 384];
        const float invN = 1.0f / (float)N_NODES;
        float m = s * invN;
        float var = ss * invN - m * m;
        float sc = gamma[d] * rsqrtf(var + BN_EPS);
        aff[d] = sc;
        aff[128 + d] = beta[d] - m * sc;
    }
}

// ---------------- combine ----------------

__global__ __launch_bounds__(256) void combine(const float* __restrict__ gsum,
                                               const float* __restrict__ aff,
                                               const int* __restrict__ gcnt,
                                               const float* __restrict__ LW,
                                               const float* __restrict__ LB,
                                               float* __restrict__ out) {
    int gid = blockIdx.x * 256 + threadIdx.x;
    if (gid >= N_GRAPHS * 128) return;
    int g = gid >> 7;
    int d = gid & 127;
    float c = (float)gcnt[g];
    float o = c * LB[0];
    #pragma unroll
    for (int l = 0; l < N_LAYERS; ++l) {
        float s = aff[(l + 1) * 256 + d];
        float t = aff[(l + 1) * 256 + 128 + d];
        o += LW[l] * (s * gsum[(l * N_GRAPHS + g) * 128 + d] + c * t);
    }
    out[gid] = o;
}

// ---------------- host launcher ----------------

extern "C" void kernel_launch(void* const* d_in, const int* in_sizes, int n_in,
                              void* d_out, int out_size, void* d_ws, size_t ws_size,
                              hipStream_t stream) {
    const float* x      = (const float*)d_in[0];
    const int*   ei     = (const int*)d_in[1];
    const int*   batch  = (const int*)d_in[2];
    const float* ini_w1 = (const float*)d_in[3];
    const float* ini_b1 = (const float*)d_in[4];
    const float* ini_w2 = (const float*)d_in[5];
    const float* ini_b2 = (const float*)d_in[6];
    const float* gw1    = (const float*)d_in[7];
    const float* gb1    = (const float*)d_in[8];
    const float* gw2    = (const float*)d_in[9];
    const float* gb2    = (const float*)d_in[10];
    const float* gamma  = (const float*)d_in[11];
    const float* beta   = (const float*)d_in[12];
    const float* lw     = (const float*)d_in[13];
    const float* lb     = (const float*)d_in[14];
    float* out = (float*)d_out;

    char* p = (char*)d_ws;
    auto carve = [&](size_t bytes) -> char* {
        char* q = p;
        p += (bytes + 255) & ~(size_t)255;
        return q;
    };
    ushort* z0   = (ushort*)carve(sizeof(ushort) * N_NODES * DIM);
    ushort* z1   = (ushort*)carve(sizeof(ushort) * N_NODES * DIM);
    float* aff   = (float*)carve(sizeof(float) * (N_LAYERS + 1) * 256);
    float* gsum  = (float*)carve(sizeof(float) * N_LAYERS * N_GRAPHS * DIM);
    float* gssq  = (float*)carve(sizeof(float) * N_LAYERS * N_GRAPHS * DIM);
    short* wbf   = (short*)carve(sizeof(short) * 10 * 128 * 128);
    int* gcnt    = (int*)carve(sizeof(int) * N_GRAPHS);
    int* cnt     = (int*)carve(sizeof(int) * N_NODES);
    ushort* slot = (ushort*)carve(sizeof(ushort) * N_NODES * SLOT_CAP);

    const int* src = ei;
    const int* dst = ei + N_EDGES;

    hipMemsetAsync(cnt, 0, sizeof(int) * N_NODES, stream);
    hipMemsetAsync(gcnt, 0, sizeof(int) * N_GRAPHS, stream);

    transpose_weights<<<(10 * 16384 + 255) / 256, 256, 0, stream>>>(
        ini_w1, ini_w2, gw1, gw2, wbf);

    build_graph<<<BG_BLOCKS, 256, 0, stream>>>(src, dst, batch, cnt, slot, gcnt,
                                               aff, gsum, gssq);

    int gblocks = (N_NODES + 63) / 64;
    gemm_mlp_ini<<<gblocks, 256, 0, stream>>>(
        x, wbf, ini_b1, wbf + 16384, ini_b2, z0);

    ushort* zprev = z0;
    ushort* znext = z1;
    for (int i = 0; i < N_LAYERS; ++i) {
        gin_layer<<<gblocks, 256, 0, stream>>>(
            zprev, cnt, slot, aff + i * 256,
            wbf + (2 + i) * 16384, gb1 + i * DIM,
            wbf + (6 + i) * 16384, gb2 + i * DIM, znext, batch,
            gsum + i * N_GRAPHS * DIM, gssq + i * N_GRAPHS * DIM);
        finalize_bn<<<1, 512, 0, stream>>>(gsum + i * N_GRAPHS * DIM,
                                           gssq + i * N_GRAPHS * DIM,
                                           gamma + i * DIM, beta + i * DIM,
                                           aff + (i + 1) * 256);
        ushort* tmp = zprev; zprev = znext; znext = tmp;
    }
    combine<<<(N_GRAPHS * 128 + 255) / 256, 256, 0, stream>>>(
        gsum, aff, gcnt, lw, lb, out);
}

// Round 2
// 522.034 us; speedup vs baseline: 1.0306x; 1.0306x over previous
//
#include <hip/hip_runtime.h>

#define N_NODES  50000
#define N_EDGES  600000
#define N_GRAPHS 512
#define DIM      128
#define N_FEAT   78
#define N_LAYERS 4
#define BN_EPS   1e-5f
#define SLOT_CAP 64
#define LDA      136

#define EDGE_BLOCKS ((N_EDGES + 255) / 256)   // 2344
#define ZERO_BLOCKS 512                       // zero 2 MB of gsum+gssq (1 MB each)
#define BG_BLOCKS (EDGE_BLOCKS + 1 + ZERO_BLOCKS)
#define TW_ELEMS (10 * 16384)

typedef __attribute__((ext_vector_type(8))) _Float16 f16x8;
typedef __attribute__((ext_vector_type(4))) float f32x4;

static __device__ __forceinline__ short f2h(float f) {
    _Float16 h = (_Float16)f;
    union { _Float16 h; short s; } u; u.h = h;
    return u.s;
}
static __device__ __forceinline__ float h2f(ushort s) {
    union { ushort s; _Float16 h; } u; u.s = s;
    return (float)u.h;
}

// ---------------- graph build: ushort slotted adjacency + gcount + bnstat/gsum zeroing ----

__global__ __launch_bounds__(256) void build_graph(const int* __restrict__ src,
                                                   const int* __restrict__ dst,
                                                   const int* __restrict__ batch,
                                                   int* __restrict__ cnt,
                                                   ushort* __restrict__ slot,
                                                   int* __restrict__ gcnt,
                                                   float* __restrict__ bnstat,
                                                   float* __restrict__ gsum,
                                                   float* __restrict__ gssq) {
    int b = blockIdx.x;
    int tid = threadIdx.x;
    if (b < EDGE_BLOCKS) {
        int e = b * 256 + tid;
        if (e < N_EDGES) {
            int d = dst[e];
            int p = atomicAdd(&cnt[d], 1);
            if (p < SLOT_CAP) slot[d * SLOT_CAP + p] = (ushort)src[e];
        }
        if (e < N_NODES) atomicAdd(&gcnt[batch[e]], 1);
    } else if (b == EDGE_BLOCKS) {
        // zero tot (4x128) + totsq (4x128) = 1024 floats
        for (int i = tid; i < 1024; i += 256) bnstat[i] = 0.0f;
    } else {
        int zb = b - EDGE_BLOCKS - 1;      // 0..511
        float4 z = make_float4(0.f, 0.f, 0.f, 0.f);
        float* base = (zb < 256) ? gsum : gssq;
        int off = (zb & 255) * 1024 + tid * 4;   // 1024 floats per block
        *(float4*)&base[off] = z;
    }
}

// ---------------- weight pre-transpose + cnt/gcnt zeroing ----------------

__global__ __launch_bounds__(256) void transpose_weights(const float* __restrict__ ini_w1,
                                                         const float* __restrict__ ini_w2,
                                                         const float* __restrict__ gw1,
                                                         const float* __restrict__ gw2,
                                                         short* __restrict__ wt,
                                                         int* __restrict__ cnt,
                                                         int* __restrict__ gcnt) {
    int gid = blockIdx.x * 256 + threadIdx.x;
    if (gid < TW_ELEMS) {
        int m = gid >> 14;
        int idx = gid & 16383;
        int n = idx >> 7;
        int k = idx & 127;
        const float* src;
        int K = 128;
        if (m == 0) { src = ini_w1; K = N_FEAT; }
        else if (m == 1) src = ini_w2;
        else if (m < 6) src = gw1 + (m - 2) * 16384;
        else src = gw2 + (m - 6) * 16384;
        float v = (k < K) ? src[k * 128 + n] : 0.f;
        wt[m * 16384 + n * 128 + k] = f2h(v);
    } else {
        int idx = gid - TW_ELEMS;
        if (idx < N_NODES) cnt[idx] = 0;
        else if (idx < N_NODES + N_GRAPHS) gcnt[idx - N_NODES] = 0;
    }
}

// ---------------- aggregation with inline BN affine ----------------
// A[n] = s ⊙ (Z[n] + Σ_{j->n} Z[j]) + (1+deg[n]) ⊙ t, where (s,t) computed
// on the fly from tot/totsq (prev layer batch stats). tot==nullptr → identity.

__global__ __launch_bounds__(256) void aggregate_h(const ushort* __restrict__ Z,
                                                   const int* __restrict__ cnt,
                                                   const ushort* __restrict__ slot,
                                                   const float* __restrict__ tot,
                                                   const float* __restrict__ totsq,
                                                   const float* __restrict__ gamma,
                                                   const float* __restrict__ beta,
                                                   ushort* __restrict__ A) {
    int node = blockIdx.x * 16 + (threadIdx.x >> 4);
    if (node >= N_NODES) return;
    int lane = threadIdx.x & 15;
    float sc[8], tc[8];
    if (tot) {
        const float invN = 1.0f / (float)N_NODES;
        #pragma unroll
        for (int j = 0; j < 8; ++j) {
            int d = lane * 8 + j;
            float m = tot[d] * invN;
            float var = totsq[d] * invN - m * m;
            float s = gamma[d] * rsqrtf(var + BN_EPS);
            sc[j] = s;
            tc[j] = beta[d] - m * s;
        }
    } else {
        #pragma unroll
        for (int j = 0; j < 8; ++j) { sc[j] = 1.0f; tc[j] = 0.0f; }
    }
    union U { uint4 u; _Float16 h[8]; };
    union I { uint4 u; ushort s[8]; };
    const uint4* z4 = (const uint4*)Z;
    U zu; zu.u = z4[node * 16 + lane];
    float v[8];
    #pragma unroll
    for (int j = 0; j < 8; ++j) v[j] = (float)zu.h[j];
    int dtrue = cnt[node];
    int d = min(dtrue, SLOT_CAP);
    const ushort* sl = slot + node * SLOT_CAP;
    int e = 0;
    for (; e + 8 <= d; e += 8) {
        I si; si.u = *(const uint4*)&sl[e];
        U u[8];
        #pragma unroll
        for (int q = 0; q < 8; ++q) u[q].u = z4[(int)si.s[q] * 16 + lane];
        #pragma unroll
        for (int j = 0; j < 8; ++j) {
            float a = ((float)u[0].h[j] + (float)u[1].h[j]) +
                      ((float)u[2].h[j] + (float)u[3].h[j]);
            float b = ((float)u[4].h[j] + (float)u[5].h[j]) +
                      ((float)u[6].h[j] + (float)u[7].h[j]);
            v[j] += a + b;
        }
    }
    if (e + 4 <= d) {
        int s0 = sl[e], s1 = sl[e + 1], s2 = sl[e + 2], s3 = sl[e + 3];
        U u0, u1, u2, u3;
        u0.u = z4[s0 * 16 + lane];
        u1.u = z4[s1 * 16 + lane];
        u2.u = z4[s2 * 16 + lane];
        u3.u = z4[s3 * 16 + lane];
        #pragma unroll
        for (int j = 0; j < 8; ++j)
            v[j] += ((float)u0.h[j] + (float)u1.h[j]) +
                    ((float)u2.h[j] + (float)u3.h[j]);
        e += 4;
    }
    for (; e < d; ++e) {
        U u; u.u = z4[(int)sl[e] * 16 + lane];
        #pragma unroll
        for (int j = 0; j < 8; ++j) v[j] += (float)u.h[j];
    }
    float dsc = 1.0f + (float)dtrue;
    U ou;
    #pragma unroll
    for (int j = 0; j < 8; ++j)
        ou.h[j] = (_Float16)(sc[j] * v[j] + dsc * tc[j]);
    ((uint4*)A)[node * 16 + lane] = ou.u;
}

// ---------------- fused 2-layer MLP: C = act2(relu(A@W1+b1)@W2+b2) ----------------
// STATS: per-graph Σ/Σ² (for pooling) + global Σ/Σ² (for BN affine of next layer)

template <int K_IN, int FP32A, int RELU2, int STATS>
__global__ __launch_bounds__(256) void gemm_mlp(const void* __restrict__ Ain,
                                                const short* __restrict__ Wt1,
                                                const float* __restrict__ b1,
                                                const short* __restrict__ Wt2,
                                                const float* __restrict__ b2,
                                                ushort* __restrict__ C,
                                                const int* __restrict__ batch,
                                                float* __restrict__ gsum,
                                                float* __restrict__ gssq,
                                                float* __restrict__ tot,
                                                float* __restrict__ totsq) {
    __shared__ short As[64 * LDA];
    __shared__ short Ws[128 * LDA];
    __shared__ int sb[64];
    int tid = threadIdx.x;
    int row0 = blockIdx.x * 64;

    #pragma unroll
    for (int j = 0; j < 8; ++j) {
        int lin = tid + j * 256;
        int n = lin >> 4;
        int kc = lin & 15;
        *(uint4*)&Ws[n * LDA + kc * 8] = *(const uint4*)&Wt1[n * 128 + kc * 8];
    }
    if (FP32A) {
        const float* A = (const float*)Ain;
        #pragma unroll
        for (int j = 0; j < 32; ++j) {
            int lin = tid + j * 256;
            int r = lin >> 7;
            int k = lin & 127;
            int gr = row0 + r;
            float v = 0.f;
            if (gr < N_NODES && k < K_IN) v = A[gr * K_IN + k];
            As[r * LDA + k] = f2h(v);
        }
    } else {
        const ushort* A = (const ushort*)Ain;
        #pragma unroll
        for (int j = 0; j < 4; ++j) {
            int lin = tid + j * 256;
            int r = lin >> 4;
            int kc = lin & 15;
            int gr = row0 + r;
            uint4 v = {0u, 0u, 0u, 0u};
            if (gr < N_NODES) v = *(const uint4*)&A[gr * 128 + kc * 8];
            *(uint4*)&As[r * LDA + kc * 8] = v;
        }
    }
    if (STATS && tid < 64) {
        int n = row0 + tid;
        sb[tid] = (n < N_NODES) ? batch[n] : -1;
    }
    __syncthreads();

    int wave = tid >> 6;
    int lane = tid & 63;
    int rw = wave >> 1;
    int cw = wave & 1;
    int lm = lane & 15;
    int quad = lane >> 4;

    f32x4 acc[2][4];
    #pragma unroll
    for (int mt = 0; mt < 2; ++mt)
        #pragma unroll
        for (int nt = 0; nt < 4; ++nt)
            acc[mt][nt] = (f32x4){0.f, 0.f, 0.f, 0.f};

    #pragma unroll
    for (int ks = 0; ks < 4; ++ks) {
        int kb = ks * 32 + quad * 8;
        f16x8 a0 = *(const f16x8*)&As[(rw * 32 + lm) * LDA + kb];
        f16x8 a1 = *(const f16x8*)&As[(rw * 32 + 16 + lm) * LDA + kb];
        #pragma unroll
        for (int nt = 0; nt < 4; ++nt) {
            f16x8 b = *(const f16x8*)&Ws[(cw * 64 + nt * 16 + lm) * LDA + kb];
            acc[0][nt] = __builtin_amdgcn_mfma_f32_16x16x32_f16(a0, b, acc[0][nt], 0, 0, 0);
            acc[1][nt] = __builtin_amdgcn_mfma_f32_16x16x32_f16(a1, b, acc[1][nt], 0, 0, 0);
        }
    }
    __syncthreads();

    ushort* Cs = (ushort*)As;
    #pragma unroll
    for (int nt = 0; nt < 4; ++nt) {
        int col = cw * 64 + nt * 16 + lm;
        float bv = b1[col];
        #pragma unroll
        for (int mt = 0; mt < 2; ++mt) {
            #pragma unroll
            for (int r = 0; r < 4; ++r) {
                int row = rw * 32 + mt * 16 + quad * 4 + r;
                Cs[row * LDA + col] = (ushort)f2h(fmaxf(acc[mt][nt][r] + bv, 0.f));
            }
        }
    }
    #pragma unroll
    for (int j = 0; j < 8; ++j) {
        int lin = tid + j * 256;
        int n = lin >> 4;
        int kc = lin & 15;
        *(uint4*)&Ws[n * LDA + kc * 8] = *(const uint4*)&Wt2[n * 128 + kc * 8];
    }
    __syncthreads();

    #pragma unroll
    for (int mt = 0; mt < 2; ++mt)
        #pragma unroll
        for (int nt = 0; nt < 4; ++nt)
            acc[mt][nt] = (f32x4){0.f, 0.f, 0.f, 0.f};
    #pragma unroll
    for (int ks = 0; ks < 4; ++ks) {
        int kb = ks * 32 + quad * 8;
        f16x8 a0 = *(const f16x8*)&As[(rw * 32 + lm) * LDA + kb];
        f16x8 a1 = *(const f16x8*)&As[(rw * 32 + 16 + lm) * LDA + kb];
        #pragma unroll
        for (int nt = 0; nt < 4; ++nt) {
            f16x8 b = *(const f16x8*)&Ws[(cw * 64 + nt * 16 + lm) * LDA + kb];
            acc[0][nt] = __builtin_amdgcn_mfma_f32_16x16x32_f16(a0, b, acc[0][nt], 0, 0, 0);
            acc[1][nt] = __builtin_amdgcn_mfma_f32_16x16x32_f16(a1, b, acc[1][nt], 0, 0, 0);
        }
    }
    __syncthreads();

    #pragma unroll
    for (int nt = 0; nt < 4; ++nt) {
        int col = cw * 64 + nt * 16 + lm;
        float bv = b2[col];
        #pragma unroll
        for (int mt = 0; mt < 2; ++mt) {
            #pragma unroll
            for (int r = 0; r < 4; ++r) {
                int row = rw * 32 + mt * 16 + quad * 4 + r;
                float o = acc[mt][nt][r] + bv;
                if (RELU2) o = fmaxf(o, 0.f);
                Cs[row * LDA + col] = (ushort)f2h(o);
            }
        }
    }
    __syncthreads();
    #pragma unroll
    for (int j = 0; j < 4; ++j) {
        int lin = tid + j * 256;
        int r = lin >> 4;
        int kc = lin & 15;
        int gr = row0 + r;
        if (gr < N_NODES)
            *(uint4*)&C[gr * 128 + kc * 8] = *(const uint4*)&Cs[r * LDA + kc * 8];
    }
    if (STATS) {
        int c = tid & 127;
        int rbase = (tid >> 7) * 32;
        int curg = sb[rbase];
        float rs = 0.f, rss = 0.f;
        float ts = 0.f, tss = 0.f;
        for (int r = rbase; r < rbase + 32; ++r) {
            int g = sb[r];
            if (g < 0) break;
            if (g != curg) {
                atomicAdd(&gsum[curg * 128 + c], rs);
                atomicAdd(&gssq[curg * 128 + c], rss);
                rs = 0.f; rss = 0.f; curg = g;
            }
            float v = h2f(Cs[r * LDA + c]);
            rs += v; rss += v * v;
            ts += v; tss += v * v;
        }
        if (curg >= 0) {
            atomicAdd(&gsum[curg * 128 + c], rs);
            atomicAdd(&gssq[curg * 128 + c], rss);
        }
        atomicAdd(&tot[c], ts);
        atomicAdd(&totsq[c], tss);
    }
}

// ---------------- combine (computes BN affine inline from tot/totsq) ----------------

__global__ __launch_bounds__(256) void combine(const float* __restrict__ gsum,
                                               const float* __restrict__ bnstat,
                                               const int* __restrict__ gcnt,
                                               const float* __restrict__ gamma,
                                               const float* __restrict__ beta,
                                               const float* __restrict__ LW,
                                               const float* __restrict__ LB,
                                               float* __restrict__ out) {
    int gid = blockIdx.x * 256 + threadIdx.x;
    if (gid >= N_GRAPHS * 128) return;
    int g = gid >> 7;
    int d = gid & 127;
    float c = (float)gcnt[g];
    float o = c * LB[0];
    const float invN = 1.0f / (float)N_NODES;
    #pragma unroll
    for (int l = 0; l < N_LAYERS; ++l) {
        float m = bnstat[l * 128 + d] * invN;
        float var = bnstat[512 + l * 128 + d] * invN - m * m;
        float s = gamma[l * 128 + d] * rsqrtf(var + BN_EPS);
        float t = beta[l * 128 + d] - m * s;
        o += LW[l] * (s * gsum[(l * N_GRAPHS + g) * 128 + d] + c * t);
    }
    out[gid] = o;
}

// ---------------- host launcher ----------------

extern "C" void kernel_launch(void* const* d_in, const int* in_sizes, int n_in,
                              void* d_out, int out_size, void* d_ws, size_t ws_size,
                              hipStream_t stream) {
    const float* x      = (const float*)d_in[0];
    const int*   ei     = (const int*)d_in[1];
    const int*   batch  = (const int*)d_in[2];
    const float* ini_w1 = (const float*)d_in[3];
    const float* ini_b1 = (const float*)d_in[4];
    const float* ini_w2 = (const float*)d_in[5];
    const float* ini_b2 = (const float*)d_in[6];
    const float* gw1    = (const float*)d_in[7];
    const float* gb1    = (const float*)d_in[8];
    const float* gw2    = (const float*)d_in[9];
    const float* gb2    = (const float*)d_in[10];
    const float* gamma  = (const float*)d_in[11];
    const float* beta   = (const float*)d_in[12];
    const float* lw     = (const float*)d_in[13];
    const float* lb     = (const float*)d_in[14];
    float* out = (float*)d_out;

    char* p = (char*)d_ws;
    auto carve = [&](size_t bytes) -> char* {
        char* q = p;
        p += (bytes + 255) & ~(size_t)255;
        return q;
    };
    ushort* z0    = (ushort*)carve(sizeof(ushort) * N_NODES * DIM);
    ushort* z1    = (ushort*)carve(sizeof(ushort) * N_NODES * DIM);
    ushort* abuf  = (ushort*)carve(sizeof(ushort) * N_NODES * DIM);
    float* bnstat = (float*)carve(sizeof(float) * 1024);   // tot[4][128] + totsq[4][128]
    float* gsum   = (float*)carve(sizeof(float) * N_LAYERS * N_GRAPHS * DIM);
    float* gssq   = (float*)carve(sizeof(float) * N_LAYERS * N_GRAPHS * DIM);
    short* wbf    = (short*)carve(sizeof(short) * 10 * 128 * 128);
    int* gcnt     = (int*)carve(sizeof(int) * N_GRAPHS);
    int* cnt      = (int*)carve(sizeof(int) * N_NODES);
    ushort* slot  = (ushort*)carve(sizeof(ushort) * N_NODES * SLOT_CAP);

    const int* src = ei;
    const int* dst = ei + N_EDGES;

    int twblocks = (TW_ELEMS + N_NODES + N_GRAPHS + 255) / 256;
    transpose_weights<<<twblocks, 256, 0, stream>>>(
        ini_w1, ini_w2, gw1, gw2, wbf, cnt, gcnt);

    build_graph<<<BG_BLOCKS, 256, 0, stream>>>(src, dst, batch, cnt, slot, gcnt,
                                               bnstat, gsum, gssq);

    int gblocks = (N_NODES + 63) / 64;
    gemm_mlp<N_FEAT, 1, 0, 0><<<gblocks, 256, 0, stream>>>(
        x, wbf, ini_b1, wbf + 16384, ini_b2, z0, nullptr, nullptr, nullptr,
        nullptr, nullptr);

    ushort* zprev = z0;
    ushort* znext = z1;
    for (int i = 0; i < N_LAYERS; ++i) {
        const float* tptr  = (i == 0) ? nullptr : bnstat + (i - 1) * 128;
        const float* tsptr = (i == 0) ? nullptr : bnstat + 512 + (i - 1) * 128;
        const float* gptr  = (i == 0) ? gamma : gamma + (i - 1) * DIM;
        const float* bptr  = (i == 0) ? beta : beta + (i - 1) * DIM;
        aggregate_h<<<(N_NODES + 15) / 16, 256, 0, stream>>>(
            zprev, cnt, slot, tptr, tsptr, gptr, bptr, abuf);
        gemm_mlp<128, 0, 1, 1><<<gblocks, 256, 0, stream>>>(
            abuf, wbf + (2 + i) * 16384, gb1 + i * DIM,
            wbf + (6 + i) * 16384, gb2 + i * DIM, znext, batch,
            gsum + i * N_GRAPHS * DIM, gssq + i * N_GRAPHS * DIM,
            bnstat + i * 128, bnstat + 512 + i * 128);
        ushort* tmp = zprev; zprev = znext; znext = tmp;
    }
    combine<<<(N_GRAPHS * 128 + 255) / 256, 256, 0, stream>>>(
        gsum, bnstat, gcnt, gamma, beta, lw, lb, out);
}

// Round 3
// 388.699 us; speedup vs baseline: 1.3841x; 1.3430x over previous
//
#include <hip/hip_runtime.h>

#define N_NODES  50000
#define N_EDGES  600000
#define N_GRAPHS 512
#define DIM      128
#define N_FEAT   78
#define N_LAYERS 4
#define BN_EPS   1e-5f
#define SLOT_CAP 64
#define LDA      136
#define NPART    16

#define EDGE_BLOCKS ((N_EDGES + 255) / 256)   // 2344
#define ZERO_BLOCKS 512                       // zero 2 MB of gsum+gssq (1 MB each)
#define BG_BLOCKS (EDGE_BLOCKS + ZERO_BLOCKS)
#define TW_ELEMS (10 * 16384)
#define BN_FLOATS (N_LAYERS * NPART * 256)    // 16384

typedef __attribute__((ext_vector_type(8))) _Float16 f16x8;
typedef __attribute__((ext_vector_type(4))) float f32x4;

static __device__ __forceinline__ short f2h(float f) {
    _Float16 h = (_Float16)f;
    union { _Float16 h; short s; } u; u.h = h;
    return u.s;
}
static __device__ __forceinline__ float h2f(ushort s) {
    union { ushort s; _Float16 h; } u; u.s = s;
    return (float)u.h;
}

// ---------------- graph build: ushort slotted adjacency + gcount + gsum/gssq zeroing ----

__global__ __launch_bounds__(256) void build_graph(const int* __restrict__ src,
                                                   const int* __restrict__ dst,
                                                   const int* __restrict__ batch,
                                                   int* __restrict__ cnt,
                                                   ushort* __restrict__ slot,
                                                   int* __restrict__ gcnt,
                                                   float* __restrict__ gsum,
                                                   float* __restrict__ gssq) {
    int b = blockIdx.x;
    int tid = threadIdx.x;
    if (b < EDGE_BLOCKS) {
        int e = b * 256 + tid;
        if (e < N_EDGES) {
            int d = dst[e];
            int p = atomicAdd(&cnt[d], 1);
            if (p < SLOT_CAP) slot[d * SLOT_CAP + p] = (ushort)src[e];
        }
        if (e < N_NODES) atomicAdd(&gcnt[batch[e]], 1);
    } else {
        int zb = b - EDGE_BLOCKS;          // 0..511
        float4 z = make_float4(0.f, 0.f, 0.f, 0.f);
        float* base = (zb < 256) ? gsum : gssq;
        int off = (zb & 255) * 1024 + tid * 4;   // 1024 floats per block
        *(float4*)&base[off] = z;
    }
}

// ---------------- weight pre-transpose + cnt/gcnt/bnstat zeroing ----------------

__global__ __launch_bounds__(256) void transpose_weights(const float* __restrict__ ini_w1,
                                                         const float* __restrict__ ini_w2,
                                                         const float* __restrict__ gw1,
                                                         const float* __restrict__ gw2,
                                                         short* __restrict__ wt,
                                                         int* __restrict__ cnt,
                                                         int* __restrict__ gcnt,
                                                         float* __restrict__ bnstat) {
    int gid = blockIdx.x * 256 + threadIdx.x;
    if (gid < TW_ELEMS) {
        int m = gid >> 14;
        int idx = gid & 16383;
        int n = idx >> 7;
        int k = idx & 127;
        const float* src;
        int K = 128;
        if (m == 0) { src = ini_w1; K = N_FEAT; }
        else if (m == 1) src = ini_w2;
        else if (m < 6) src = gw1 + (m - 2) * 16384;
        else src = gw2 + (m - 6) * 16384;
        float v = (k < K) ? src[k * 128 + n] : 0.f;
        wt[m * 16384 + n * 128 + k] = f2h(v);
    } else {
        int idx = gid - TW_ELEMS;
        if (idx < N_NODES) cnt[idx] = 0;
        else if (idx < N_NODES + N_GRAPHS) gcnt[idx - N_NODES] = 0;
        else {
            int bi = idx - N_NODES - N_GRAPHS;
            if (bi < BN_FLOATS) bnstat[bi] = 0.0f;
        }
    }
}

// ---------------- aggregation with inline BN affine (from 16-way partials) ---------
// A[n] = s ⊙ (Z[n] + Σ_{j->n} Z[j]) + (1+deg[n]) ⊙ t

__global__ __launch_bounds__(256) void aggregate_h(const ushort* __restrict__ Z,
                                                   const int* __restrict__ cnt,
                                                   const ushort* __restrict__ slot,
                                                   const float* __restrict__ bnpart,
                                                   const float* __restrict__ gamma,
                                                   const float* __restrict__ beta,
                                                   ushort* __restrict__ A) {
    __shared__ float saff[128], taff[128];
    int tid = threadIdx.x;
    if (tid < 128) {
        float s = 1.0f, t = 0.0f;
        if (bnpart) {
            float sum = 0.f, ssq = 0.f;
            #pragma unroll
            for (int p = 0; p < NPART; ++p) {
                sum += bnpart[p * 256 + tid];
                ssq += bnpart[p * 256 + 128 + tid];
            }
            const float invN = 1.0f / (float)N_NODES;
            float m = sum * invN;
            float var = ssq * invN - m * m;
            s = gamma[tid] * rsqrtf(var + BN_EPS);
            t = beta[tid] - m * s;
        }
        saff[tid] = s; taff[tid] = t;
    }
    __syncthreads();

    int node = blockIdx.x * 16 + (tid >> 4);
    if (node >= N_NODES) return;   // never taken (50000 = 3125*16), kept for safety
    int lane = tid & 15;
    float sc[8], tc[8];
    #pragma unroll
    for (int j = 0; j < 8; ++j) {
        sc[j] = saff[lane * 8 + j];
        tc[j] = taff[lane * 8 + j];
    }
    union U { uint4 u; _Float16 h[8]; };
    union I { uint4 u; ushort s[8]; };
    const uint4* z4 = (const uint4*)Z;
    U zu; zu.u = z4[node * 16 + lane];
    float v[8];
    #pragma unroll
    for (int j = 0; j < 8; ++j) v[j] = (float)zu.h[j];
    int dtrue = cnt[node];
    int d = min(dtrue, SLOT_CAP);
    const ushort* sl = slot + node * SLOT_CAP;
    int e = 0;
    for (; e + 8 <= d; e += 8) {
        I si; si.u = *(const uint4*)&sl[e];
        U u[8];
        #pragma unroll
        for (int q = 0; q < 8; ++q) u[q].u = z4[(int)si.s[q] * 16 + lane];
        #pragma unroll
        for (int j = 0; j < 8; ++j) {
            float a = ((float)u[0].h[j] + (float)u[1].h[j]) +
                      ((float)u[2].h[j] + (float)u[3].h[j]);
            float b = ((float)u[4].h[j] + (float)u[5].h[j]) +
                      ((float)u[6].h[j] + (float)u[7].h[j]);
            v[j] += a + b;
        }
    }
    if (e + 4 <= d) {
        int s0 = sl[e], s1 = sl[e + 1], s2 = sl[e + 2], s3 = sl[e + 3];
        U u0, u1, u2, u3;
        u0.u = z4[s0 * 16 + lane];
        u1.u = z4[s1 * 16 + lane];
        u2.u = z4[s2 * 16 + lane];
        u3.u = z4[s3 * 16 + lane];
        #pragma unroll
        for (int j = 0; j < 8; ++j)
            v[j] += ((float)u0.h[j] + (float)u1.h[j]) +
                    ((float)u2.h[j] + (float)u3.h[j]);
        e += 4;
    }
    for (; e < d; ++e) {
        U u; u.u = z4[(int)sl[e] * 16 + lane];
        #pragma unroll
        for (int j = 0; j < 8; ++j) v[j] += (float)u.h[j];
    }
    float dsc = 1.0f + (float)dtrue;
    U ou;
    #pragma unroll
    for (int j = 0; j < 8; ++j)
        ou.h[j] = (_Float16)(sc[j] * v[j] + dsc * tc[j]);
    ((uint4*)A)[node * 16 + lane] = ou.u;
}

// ---------------- fused 2-layer MLP: C = act2(relu(A@W1+b1)@W2+b2) ----------------
// W1/W2 consumed as register fragments straight from L2 (no LDS staging).
// LDS: As (input / GEMM2 output) + Bs (GEMM1 output) ping-pong, ~35 KB -> 4 blocks/CU.

template <int K_IN, int FP32A, int RELU2, int STATS>
__global__ __launch_bounds__(256, 4) void gemm_mlp(const void* __restrict__ Ain,
                                                   const short* __restrict__ Wt1,
                                                   const float* __restrict__ b1,
                                                   const short* __restrict__ Wt2,
                                                   const float* __restrict__ b2,
                                                   ushort* __restrict__ C,
                                                   const int* __restrict__ batch,
                                                   float* __restrict__ gsum,
                                                   float* __restrict__ gssq,
                                                   float* __restrict__ bnpart) {
    __shared__ short As[64 * LDA];   // input A, later GEMM2 output
    __shared__ short Bs[64 * LDA];   // GEMM1 output (relu), GEMM2 input; later float scratch
    __shared__ int sb[64];
    int tid = threadIdx.x;
    int row0 = blockIdx.x * 64;

    int wave = tid >> 6;
    int wlane = tid & 63;
    int rw = wave >> 1;
    int cw = wave & 1;
    int lm = wlane & 15;
    int quad = wlane >> 4;
    const int wrow = (cw * 64 + lm) * 128 + quad * 8;   // W fragment base (elements)

    // issue first W1 k-slice loads early (overlap with A staging)
    f16x8 bcur[4], bnxt[4];
    #pragma unroll
    for (int nt = 0; nt < 4; ++nt)
        bcur[nt] = *(const f16x8*)&Wt1[wrow + nt * 16 * 128];

    if (FP32A) {
        const float* A = (const float*)Ain;
        #pragma unroll
        for (int j = 0; j < 32; ++j) {
            int lin = tid + j * 256;
            int r = lin >> 7;
            int k = lin & 127;
            int gr = row0 + r;
            float v = 0.f;
            if (gr < N_NODES && k < K_IN) v = A[gr * K_IN + k];
            As[r * LDA + k] = f2h(v);
        }
    } else {
        const ushort* A = (const ushort*)Ain;
        #pragma unroll
        for (int j = 0; j < 4; ++j) {
            int lin = tid + j * 256;
            int r = lin >> 4;
            int kc = lin & 15;
            int gr = row0 + r;
            uint4 v = {0u, 0u, 0u, 0u};
            if (gr < N_NODES) v = *(const uint4*)&A[gr * 128 + kc * 8];
            *(uint4*)&As[r * LDA + kc * 8] = v;
        }
    }
    if (STATS && tid < 64) {
        int n = row0 + tid;
        sb[tid] = (n < N_NODES) ? batch[n] : -1;
    }
    __syncthreads();   // s1: As ready

    // ---- GEMM 1: Bs = relu(As @ W1 + b1) ----
    f32x4 acc[2][4];
    #pragma unroll
    for (int mt = 0; mt < 2; ++mt)
        #pragma unroll
        for (int nt = 0; nt < 4; ++nt)
            acc[mt][nt] = (f32x4){0.f, 0.f, 0.f, 0.f};

    #pragma unroll
    for (int ks = 0; ks < 4; ++ks) {
        if (ks < 3) {
            #pragma unroll
            for (int nt = 0; nt < 4; ++nt)
                bnxt[nt] = *(const f16x8*)&Wt1[wrow + nt * 16 * 128 + (ks + 1) * 32];
        }
        int kb = ks * 32 + quad * 8;
        f16x8 a0 = *(const f16x8*)&As[(rw * 32 + lm) * LDA + kb];
        f16x8 a1 = *(const f16x8*)&As[(rw * 32 + 16 + lm) * LDA + kb];
        #pragma unroll
        for (int nt = 0; nt < 4; ++nt) {
            acc[0][nt] = __builtin_amdgcn_mfma_f32_16x16x32_f16(a0, bcur[nt], acc[0][nt], 0, 0, 0);
            acc[1][nt] = __builtin_amdgcn_mfma_f32_16x16x32_f16(a1, bcur[nt], acc[1][nt], 0, 0, 0);
        }
        #pragma unroll
        for (int nt = 0; nt < 4; ++nt) bcur[nt] = bnxt[nt];
    }

    // GEMM1 output -> Bs (fresh region, no barrier needed before write)
    #pragma unroll
    for (int nt = 0; nt < 4; ++nt) {
        int col = cw * 64 + nt * 16 + lm;
        float bv = b1[col];
        #pragma unroll
        for (int mt = 0; mt < 2; ++mt) {
            #pragma unroll
            for (int r = 0; r < 4; ++r) {
                int row = rw * 32 + mt * 16 + quad * 4 + r;
                Bs[row * LDA + col] = (short)f2h(fmaxf(acc[mt][nt][r] + bv, 0.f));
            }
        }
    }
    // prefetch first W2 k-slice while Bs settles
    #pragma unroll
    for (int nt = 0; nt < 4; ++nt)
        bcur[nt] = *(const f16x8*)&Wt2[wrow + nt * 16 * 128];
    __syncthreads();   // s2: Bs ready (also: all As reads done)

    // ---- GEMM 2: As = act2(Bs @ W2 + b2) ----
    #pragma unroll
    for (int mt = 0; mt < 2; ++mt)
        #pragma unroll
        for (int nt = 0; nt < 4; ++nt)
            acc[mt][nt] = (f32x4){0.f, 0.f, 0.f, 0.f};
    #pragma unroll
    for (int ks = 0; ks < 4; ++ks) {
        if (ks < 3) {
            #pragma unroll
            for (int nt = 0; nt < 4; ++nt)
                bnxt[nt] = *(const f16x8*)&Wt2[wrow + nt * 16 * 128 + (ks + 1) * 32];
        }
        int kb = ks * 32 + quad * 8;
        f16x8 a0 = *(const f16x8*)&Bs[(rw * 32 + lm) * LDA + kb];
        f16x8 a1 = *(const f16x8*)&Bs[(rw * 32 + 16 + lm) * LDA + kb];
        #pragma unroll
        for (int nt = 0; nt < 4; ++nt) {
            acc[0][nt] = __builtin_amdgcn_mfma_f32_16x16x32_f16(a0, bcur[nt], acc[0][nt], 0, 0, 0);
            acc[1][nt] = __builtin_amdgcn_mfma_f32_16x16x32_f16(a1, bcur[nt], acc[1][nt], 0, 0, 0);
        }
        #pragma unroll
        for (int nt = 0; nt < 4; ++nt) bcur[nt] = bnxt[nt];
    }

    ushort* Cs = (ushort*)As;   // GEMM2 output goes back into the As region
    #pragma unroll
    for (int nt = 0; nt < 4; ++nt) {
        int col = cw * 64 + nt * 16 + lm;
        float bv = b2[col];
        #pragma unroll
        for (int mt = 0; mt < 2; ++mt) {
            #pragma unroll
            for (int r = 0; r < 4; ++r) {
                int row = rw * 32 + mt * 16 + quad * 4 + r;
                float o = acc[mt][nt][r] + bv;
                if (RELU2) o = fmaxf(o, 0.f);
                Cs[row * LDA + col] = (ushort)f2h(o);
            }
        }
    }
    __syncthreads();   // s3: output tile ready (all Bs reads done)

    #pragma unroll
    for (int j = 0; j < 4; ++j) {
        int lin = tid + j * 256;
        int r = lin >> 4;
        int kc = lin & 15;
        int gr = row0 + r;
        if (gr < N_NODES)
            *(uint4*)&C[gr * 128 + kc * 8] = *(const uint4*)&Cs[r * LDA + kc * 8];
    }
    if (STATS) {
        int c = tid & 127;
        int rbase = (tid >> 7) * 32;
        int curg = sb[rbase];
        float rs = 0.f, rss = 0.f;
        float ts = 0.f, tss = 0.f;
        for (int r = rbase; r < rbase + 32; ++r) {
            int g = sb[r];
            if (g < 0) break;
            if (g != curg) {
                atomicAdd(&gsum[curg * 128 + c], rs);
                atomicAdd(&gssq[curg * 128 + c], rss);
                rs = 0.f; rss = 0.f; curg = g;
            }
            float v = h2f(Cs[r * LDA + c]);
            rs += v; rss += v * v;
            ts += v; tss += v * v;
        }
        if (curg >= 0) {
            atomicAdd(&gsum[curg * 128 + c], rs);
            atomicAdd(&gssq[curg * 128 + c], rss);
        }
        // pair the two strips through LDS, then one atomic per column into
        // the block's 16-way-privatized partial slot (depth ~49 per address)
        float* scr = (float*)Bs;
        if (tid >= 128) { scr[c] = ts; scr[128 + c] = tss; }
        __syncthreads();   // s4
        if (tid < 128) {
            float* part = bnpart + (blockIdx.x & (NPART - 1)) * 256;
            atomicAdd(&part[c], ts + scr[c]);
            atomicAdd(&part[128 + c], tss + scr[128 + c]);
        }
    }
}

// ---------------- combine (BN affine inline from 16-way partials) ----------------

__global__ __launch_bounds__(256) void combine(const float* __restrict__ gsum,
                                               const float* __restrict__ bnstat,
                                               const int* __restrict__ gcnt,
                                               const float* __restrict__ gamma,
                                               const float* __restrict__ beta,
                                               const float* __restrict__ LW,
                                               const float* __restrict__ LB,
                                               float* __restrict__ out) {
    int gid = blockIdx.x * 256 + threadIdx.x;
    if (gid >= N_GRAPHS * 128) return;
    int g = gid >> 7;
    int d = gid & 127;
    float c = (float)gcnt[g];
    float o = c * LB[0];
    const float invN = 1.0f / (float)N_NODES;
    #pragma unroll
    for (int l = 0; l < N_LAYERS; ++l) {
        const float* part = bnstat + l * NPART * 256;
        float sum = 0.f, ssq = 0.f;
        #pragma unroll
        for (int p = 0; p < NPART; ++p) {
            sum += part[p * 256 + d];
            ssq += part[p * 256 + 128 + d];
        }
        float m = sum * invN;
        float var = ssq * invN - m * m;
        float s = gamma[l * 128 + d] * rsqrtf(var + BN_EPS);
        float t = beta[l * 128 + d] - m * s;
        o += LW[l] * (s * gsum[(l * N_GRAPHS + g) * 128 + d] + c * t);
    }
    out[gid] = o;
}

// ---------------- host launcher ----------------

extern "C" void kernel_launch(void* const* d_in, const int* in_sizes, int n_in,
                              void* d_out, int out_size, void* d_ws, size_t ws_size,
                              hipStream_t stream) {
    const float* x      = (const float*)d_in[0];
    const int*   ei     = (const int*)d_in[1];
    const int*   batch  = (const int*)d_in[2];
    const float* ini_w1 = (const float*)d_in[3];
    const float* ini_b1 = (const float*)d_in[4];
    const float* ini_w2 = (const float*)d_in[5];
    const float* ini_b2 = (const float*)d_in[6];
    const float* gw1    = (const float*)d_in[7];
    const float* gb1    = (const float*)d_in[8];
    const float* gw2    = (const float*)d_in[9];
    const float* gb2    = (const float*)d_in[10];
    const float* gamma  = (const float*)d_in[11];
    const float* beta   = (const float*)d_in[12];
    const float* lw     = (const float*)d_in[13];
    const float* lb     = (const float*)d_in[14];
    float* out = (float*)d_out;

    char* p = (char*)d_ws;
    auto carve = [&](size_t bytes) -> char* {
        char* q = p;
        p += (bytes + 255) & ~(size_t)255;
        return q;
    };
    ushort* z0    = (ushort*)carve(sizeof(ushort) * N_NODES * DIM);
    ushort* z1    = (ushort*)carve(sizeof(ushort) * N_NODES * DIM);
    ushort* abuf  = (ushort*)carve(sizeof(ushort) * N_NODES * DIM);
    float* bnstat = (float*)carve(sizeof(float) * BN_FLOATS);  // 4 layers x 16 parts x 256
    float* gsum   = (float*)carve(sizeof(float) * N_LAYERS * N_GRAPHS * DIM);
    float* gssq   = (float*)carve(sizeof(float) * N_LAYERS * N_GRAPHS * DIM);
    short* wbf    = (short*)carve(sizeof(short) * 10 * 128 * 128);
    int* gcnt     = (int*)carve(sizeof(int) * N_GRAPHS);
    int* cnt      = (int*)carve(sizeof(int) * N_NODES);
    ushort* slot  = (ushort*)carve(sizeof(ushort) * N_NODES * SLOT_CAP);

    const int* src = ei;
    const int* dst = ei + N_EDGES;

    int twblocks = (TW_ELEMS + N_NODES + N_GRAPHS + BN_FLOATS + 255) / 256;
    transpose_weights<<<twblocks, 256, 0, stream>>>(
        ini_w1, ini_w2, gw1, gw2, wbf, cnt, gcnt, bnstat);

    build_graph<<<BG_BLOCKS, 256, 0, stream>>>(src, dst, batch, cnt, slot, gcnt,
                                               gsum, gssq);

    int gblocks = (N_NODES + 63) / 64;
    gemm_mlp<N_FEAT, 1, 0, 0><<<gblocks, 256, 0, stream>>>(
        x, wbf, ini_b1, wbf + 16384, ini_b2, z0, nullptr, nullptr, nullptr,
        nullptr);

    ushort* zprev = z0;
    ushort* znext = z1;
    for (int i = 0; i < N_LAYERS; ++i) {
        const float* bp_in = (i == 0) ? nullptr : bnstat + (i - 1) * NPART * 256;
        const float* gptr  = (i == 0) ? gamma : gamma + (i - 1) * DIM;
        const float* bptr  = (i == 0) ? beta : beta + (i - 1) * DIM;
        aggregate_h<<<(N_NODES + 15) / 16, 256, 0, stream>>>(
            zprev, cnt, slot, bp_in, gptr, bptr, abuf);
        gemm_mlp<128, 0, 1, 1><<<gblocks, 256, 0, stream>>>(
            abuf, wbf + (2 + i) * 16384, gb1 + i * DIM,
            wbf + (6 + i) * 16384, gb2 + i * DIM, znext, batch,
            gsum + i * N_GRAPHS * DIM, gssq + i * N_GRAPHS * DIM,
            bnstat + i * NPART * 256);
        ushort* tmp = zprev; zprev = znext; znext = tmp;
    }
    combine<<<(N_GRAPHS * 128 + 255) / 256, 256, 0, stream>>>(
        gsum, bnstat, gcnt, gamma, beta, lw, lb, out);
}

// Round 4
// 383.868 us; speedup vs baseline: 1.4016x; 1.0126x over previous
//
#include <hip/hip_runtime.h>

#define N_NODES  50000
#define N_EDGES  600000
#define N_GRAPHS 512
#define DIM      128
#define N_FEAT   78
#define N_LAYERS 4
#define BN_EPS   1e-5f
#define SLOT_CAP 64
#define LDA      136
#define NPART    16

#define EDGE_BLOCKS ((N_EDGES + 255) / 256)   // 2344
#define ZERO_BLOCKS 512                       // zero 2 MB of gsum+gssq
#define BG_BLOCKS (EDGE_BLOCKS + ZERO_BLOCKS) // 2856
#define GBLOCKS ((N_NODES + 63) / 64)         // 782
#define TW_ELEMS (10 * 16384)
#define BN_FLOATS (N_LAYERS * NPART * 256)    // 16384

typedef __attribute__((ext_vector_type(8))) _Float16 f16x8;
typedef __attribute__((ext_vector_type(4))) float f32x4;

static __device__ __forceinline__ short f2h(float f) {
    _Float16 h = (_Float16)f;
    union { _Float16 h; short s; } u; u.h = h;
    return u.s;
}
static __device__ __forceinline__ float h2f(ushort s) {
    union { ushort s; _Float16 h; } u; u.s = s;
    return (float)u.h;
}

// ---------------- weight pre-transpose + bnstat zeroing ----------------

__global__ __launch_bounds__(256) void transpose_weights(const float* __restrict__ ini_w1,
                                                         const float* __restrict__ ini_w2,
                                                         const float* __restrict__ gw1,
                                                         const float* __restrict__ gw2,
                                                         short* __restrict__ wt,
                                                         float* __restrict__ bnstat) {
    int gid = blockIdx.x * 256 + threadIdx.x;
    if (gid < TW_ELEMS) {
        int m = gid >> 14;
        int idx = gid & 16383;
        int n = idx >> 7;
        int k = idx & 127;
        const float* src;
        int K = 128;
        if (m == 0) { src = ini_w1; K = N_FEAT; }
        else if (m == 1) src = ini_w2;
        else if (m < 6) src = gw1 + (m - 2) * 16384;
        else src = gw2 + (m - 6) * 16384;
        float v = (k < K) ? src[k * 128 + n] : 0.f;
        wt[m * 16384 + n * 128 + k] = f2h(v);
    } else {
        int bi = gid - TW_ELEMS;
        if (bi < BN_FLOATS) bnstat[bi] = 0.0f;
    }
}

// ---------------- fused: initial MLP (blocks 0..GBLOCKS-1) + graph build ----------
// The two halves are fully independent: gemm_ini needs wbf (from transpose_weights);
// build needs cnt/gcnt zeroed (hipMemsetAsync before). Co-scheduling overlaps the
// latency-bound atomic stream of build with the latency-bound MFMA/staging of gemm.

__global__ __launch_bounds__(256, 4) void ini_fused(const float* __restrict__ x,
                                                    const short* __restrict__ Wt1,
                                                    const float* __restrict__ b1,
                                                    const short* __restrict__ Wt2,
                                                    const float* __restrict__ b2,
                                                    ushort* __restrict__ Cout,
                                                    const int* __restrict__ src,
                                                    const int* __restrict__ dst,
                                                    const int* __restrict__ batch,
                                                    int* __restrict__ cnt,
                                                    ushort* __restrict__ slot,
                                                    int* __restrict__ gcnt,
                                                    float* __restrict__ gsum,
                                                    float* __restrict__ gssq) {
    __shared__ short As[64 * LDA];
    __shared__ short Bs[64 * LDA];
    int tid = threadIdx.x;

    if (blockIdx.x >= GBLOCKS) {
        // ---- graph-build part ----
        int b = blockIdx.x - GBLOCKS;
        if (b < EDGE_BLOCKS) {
            int e = b * 256 + tid;
            if (e < N_EDGES) {
                int d = dst[e];
                int p = atomicAdd(&cnt[d], 1);
                if (p < SLOT_CAP) slot[d * SLOT_CAP + p] = (ushort)src[e];
            }
            if (e < N_NODES) atomicAdd(&gcnt[batch[e]], 1);
        } else {
            int zb = b - EDGE_BLOCKS;          // 0..511
            float4 z = make_float4(0.f, 0.f, 0.f, 0.f);
            float* base = (zb < 256) ? gsum : gssq;
            int off = (zb & 255) * 1024 + tid * 4;
            *(float4*)&base[off] = z;
        }
        return;
    }

    // ---- gemm_ini part: C = relu(A@W1+b1)@W2+b2, A fp32 [N,78] ----
    int row0 = blockIdx.x * 64;
    int wave = tid >> 6;
    int wlane = tid & 63;
    int rw = wave >> 1;
    int cw = wave & 1;
    int lm = wlane & 15;
    int quad = wlane >> 4;
    const int wrow = (cw * 64 + lm) * 128 + quad * 8;

    f16x8 bcur[4], bnxt[4];
    #pragma unroll
    for (int nt = 0; nt < 4; ++nt)
        bcur[nt] = *(const f16x8*)&Wt1[wrow + nt * 2048];

    #pragma unroll
    for (int j = 0; j < 32; ++j) {
        int lin = tid + j * 256;
        int r = lin >> 7;
        int k = lin & 127;
        int gr = row0 + r;
        float v = 0.f;
        if (gr < N_NODES && k < N_FEAT) v = x[gr * N_FEAT + k];
        As[r * LDA + k] = f2h(v);
    }
    __syncthreads();   // As ready

    f32x4 acc[2][4];
    #pragma unroll
    for (int mt = 0; mt < 2; ++mt)
        #pragma unroll
        for (int nt = 0; nt < 4; ++nt)
            acc[mt][nt] = (f32x4){0.f, 0.f, 0.f, 0.f};

    #pragma unroll
    for (int ks = 0; ks < 4; ++ks) {
        if (ks < 3) {
            #pragma unroll
            for (int nt = 0; nt < 4; ++nt)
                bnxt[nt] = *(const f16x8*)&Wt1[wrow + nt * 2048 + (ks + 1) * 32];
        }
        int kb = ks * 32 + quad * 8;
        f16x8 a0 = *(const f16x8*)&As[(rw * 32 + lm) * LDA + kb];
        f16x8 a1 = *(const f16x8*)&As[(rw * 32 + 16 + lm) * LDA + kb];
        #pragma unroll
        for (int nt = 0; nt < 4; ++nt) {
            acc[0][nt] = __builtin_amdgcn_mfma_f32_16x16x32_f16(a0, bcur[nt], acc[0][nt], 0, 0, 0);
            acc[1][nt] = __builtin_amdgcn_mfma_f32_16x16x32_f16(a1, bcur[nt], acc[1][nt], 0, 0, 0);
        }
        #pragma unroll
        for (int nt = 0; nt < 4; ++nt) bcur[nt] = bnxt[nt];
    }

    #pragma unroll
    for (int nt = 0; nt < 4; ++nt) {
        int col = cw * 64 + nt * 16 + lm;
        float bv = b1[col];
        #pragma unroll
        for (int mt = 0; mt < 2; ++mt) {
            #pragma unroll
            for (int r = 0; r < 4; ++r) {
                int row = rw * 32 + mt * 16 + quad * 4 + r;
                Bs[row * LDA + col] = (short)f2h(fmaxf(acc[mt][nt][r] + bv, 0.f));
            }
        }
    }
    #pragma unroll
    for (int nt = 0; nt < 4; ++nt)
        bcur[nt] = *(const f16x8*)&Wt2[wrow + nt * 2048];
    __syncthreads();   // Bs ready

    #pragma unroll
    for (int mt = 0; mt < 2; ++mt)
        #pragma unroll
        for (int nt = 0; nt < 4; ++nt)
            acc[mt][nt] = (f32x4){0.f, 0.f, 0.f, 0.f};
    #pragma unroll
    for (int ks = 0; ks < 4; ++ks) {
        if (ks < 3) {
            #pragma unroll
            for (int nt = 0; nt < 4; ++nt)
                bnxt[nt] = *(const f16x8*)&Wt2[wrow + nt * 2048 + (ks + 1) * 32];
        }
        int kb = ks * 32 + quad * 8;
        f16x8 a0 = *(const f16x8*)&Bs[(rw * 32 + lm) * LDA + kb];
        f16x8 a1 = *(const f16x8*)&Bs[(rw * 32 + 16 + lm) * LDA + kb];
        #pragma unroll
        for (int nt = 0; nt < 4; ++nt) {
            acc[0][nt] = __builtin_amdgcn_mfma_f32_16x16x32_f16(a0, bcur[nt], acc[0][nt], 0, 0, 0);
            acc[1][nt] = __builtin_amdgcn_mfma_f32_16x16x32_f16(a1, bcur[nt], acc[1][nt], 0, 0, 0);
        }
        #pragma unroll
        for (int nt = 0; nt < 4; ++nt) bcur[nt] = bnxt[nt];
    }

    ushort* Cs = (ushort*)As;
    #pragma unroll
    for (int nt = 0; nt < 4; ++nt) {
        int col = cw * 64 + nt * 16 + lm;
        float bv = b2[col];
        #pragma unroll
        for (int mt = 0; mt < 2; ++mt) {
            #pragma unroll
            for (int r = 0; r < 4; ++r) {
                int row = rw * 32 + mt * 16 + quad * 4 + r;
                Cs[row * LDA + col] = (ushort)f2h(acc[mt][nt][r] + bv);
            }
        }
    }
    __syncthreads();   // Cs ready

    #pragma unroll
    for (int j = 0; j < 4; ++j) {
        int lin = tid + j * 256;
        int r = lin >> 4;
        int kc = lin & 15;
        int gr = row0 + r;
        if (gr < N_NODES)
            *(uint4*)&Cout[gr * 128 + kc * 8] = *(const uint4*)&Cs[r * LDA + kc * 8];
    }
}

// ---------------- aggregation with inline BN affine (from 16-way partials) ---------
// A[n] = s ⊙ (Z[n] + Σ_{j->n} Z[j]) + (1+deg[n]) ⊙ t

__global__ __launch_bounds__(256) void aggregate_h(const ushort* __restrict__ Z,
                                                   const int* __restrict__ cnt,
                                                   const ushort* __restrict__ slot,
                                                   const float* __restrict__ bnpart,
                                                   const float* __restrict__ gamma,
                                                   const float* __restrict__ beta,
                                                   ushort* __restrict__ A) {
    __shared__ float saff[128], taff[128];
    int tid = threadIdx.x;
    if (tid < 128) {
        float s = 1.0f, t = 0.0f;
        if (bnpart) {
            float sum = 0.f, ssq = 0.f;
            #pragma unroll
            for (int p = 0; p < NPART; ++p) {
                sum += bnpart[p * 256 + tid];
                ssq += bnpart[p * 256 + 128 + tid];
            }
            const float invN = 1.0f / (float)N_NODES;
            float m = sum * invN;
            float var = ssq * invN - m * m;
            s = gamma[tid] * rsqrtf(var + BN_EPS);
            t = beta[tid] - m * s;
        }
        saff[tid] = s; taff[tid] = t;
    }
    __syncthreads();

    int node = blockIdx.x * 16 + (tid >> 4);
    if (node >= N_NODES) return;
    int lane = tid & 15;
    float sc[8], tc[8];
    #pragma unroll
    for (int j = 0; j < 8; ++j) {
        sc[j] = saff[lane * 8 + j];
        tc[j] = taff[lane * 8 + j];
    }
    union U { uint4 u; _Float16 h[8]; };
    union I { uint4 u; ushort s[8]; };
    const uint4* z4 = (const uint4*)Z;
    U zu; zu.u = z4[node * 16 + lane];
    float v[8];
    #pragma unroll
    for (int j = 0; j < 8; ++j) v[j] = (float)zu.h[j];
    int dtrue = cnt[node];
    int d = min(dtrue, SLOT_CAP);
    const ushort* sl = slot + node * SLOT_CAP;
    int e = 0;
    for (; e + 8 <= d; e += 8) {
        I si; si.u = *(const uint4*)&sl[e];
        U u[8];
        #pragma unroll
        for (int q = 0; q < 8; ++q) u[q].u = z4[(int)si.s[q] * 16 + lane];
        #pragma unroll
        for (int j = 0; j < 8; ++j) {
            float a = ((float)u[0].h[j] + (float)u[1].h[j]) +
                      ((float)u[2].h[j] + (float)u[3].h[j]);
            float b = ((float)u[4].h[j] + (float)u[5].h[j]) +
                      ((float)u[6].h[j] + (float)u[7].h[j]);
            v[j] += a + b;
        }
    }
    if (e + 4 <= d) {
        int s0 = sl[e], s1 = sl[e + 1], s2 = sl[e + 2], s3 = sl[e + 3];
        U u0, u1, u2, u3;
        u0.u = z4[s0 * 16 + lane];
        u1.u = z4[s1 * 16 + lane];
        u2.u = z4[s2 * 16 + lane];
        u3.u = z4[s3 * 16 + lane];
        #pragma unroll
        for (int j = 0; j < 8; ++j)
            v[j] += ((float)u0.h[j] + (float)u1.h[j]) +
                    ((float)u2.h[j] + (float)u3.h[j]);
        e += 4;
    }
    for (; e < d; ++e) {
        U u; u.u = z4[(int)sl[e] * 16 + lane];
        #pragma unroll
        for (int j = 0; j < 8; ++j) v[j] += (float)u.h[j];
    }
    float dsc = 1.0f + (float)dtrue;
    U ou;
    #pragma unroll
    for (int j = 0; j < 8; ++j)
        ou.h[j] = (_Float16)(sc[j] * v[j] + dsc * tc[j]);
    ((uint4*)A)[node * 16 + lane] = ou.u;
}

// ---------------- GIN MLP: C = relu(relu(A@W1+b1)@W2+b2), A fp16 [N,128] ----------
// A-operand read DIRECTLY from global (16 full lines per wave-load — perfectly
// coalesced), W from registers, LDS only for the GEMM1->GEMM2 handoff + C staging.
// LDS ~19 KB; occupancy VGPR-capped at 16 waves/CU (was LDS-capped at 12).

__global__ __launch_bounds__(256, 4) void gemm_gin(const ushort* __restrict__ A,
                                                   const short* __restrict__ Wt1,
                                                   const float* __restrict__ b1,
                                                   const short* __restrict__ Wt2,
                                                   const float* __restrict__ b2,
                                                   ushort* __restrict__ C,
                                                   const int* __restrict__ batch,
                                                   float* __restrict__ gsum,
                                                   float* __restrict__ gssq,
                                                   float* __restrict__ bnpart) {
    __shared__ short Bs[64 * LDA];    // GEMM1 out / GEMM2 in, then C staging
    __shared__ float scr[256];
    __shared__ int sb[64];
    int tid = threadIdx.x;
    int row0 = blockIdx.x * 64;

    int wave = tid >> 6;
    int wlane = tid & 63;
    int rw = wave >> 1;
    int cw = wave & 1;
    int lm = wlane & 15;
    int quad = wlane >> 4;
    const int wrow = (cw * 64 + lm) * 128 + quad * 8;

    if (tid < 64) {
        int n = row0 + tid;
        sb[tid] = (n < N_NODES) ? batch[n] : -1;
    }

    // A fragment pointers (row-clamped; duplicate last row for OOB tiles — rows
    // >= N_NODES never reach C or stats)
    int r0 = min(row0 + rw * 32 + lm, N_NODES - 1);
    int r1 = min(row0 + rw * 32 + 16 + lm, N_NODES - 1);
    const ushort* arow0 = A + r0 * 128 + quad * 8;
    const ushort* arow1 = A + r1 * 128 + quad * 8;

    f16x8 bcur[4], bnxt[4];
    #pragma unroll
    for (int nt = 0; nt < 4; ++nt)
        bcur[nt] = *(const f16x8*)&Wt1[wrow + nt * 2048];

    f32x4 acc[2][4];
    #pragma unroll
    for (int mt = 0; mt < 2; ++mt)
        #pragma unroll
        for (int nt = 0; nt < 4; ++nt)
            acc[mt][nt] = (f32x4){0.f, 0.f, 0.f, 0.f};

    // ---- GEMM 1: acc = A @ W1 (A straight from global; no barrier needed) ----
    f16x8 a0 = *(const f16x8*)arow0;
    f16x8 a1 = *(const f16x8*)arow1;
    #pragma unroll
    for (int ks = 0; ks < 4; ++ks) {
        f16x8 a0n, a1n;
        if (ks < 3) {
            a0n = *(const f16x8*)(arow0 + (ks + 1) * 32);
            a1n = *(const f16x8*)(arow1 + (ks + 1) * 32);
            #pragma unroll
            for (int nt = 0; nt < 4; ++nt)
                bnxt[nt] = *(const f16x8*)&Wt1[wrow + nt * 2048 + (ks + 1) * 32];
        }
        #pragma unroll
        for (int nt = 0; nt < 4; ++nt) {
            acc[0][nt] = __builtin_amdgcn_mfma_f32_16x16x32_f16(a0, bcur[nt], acc[0][nt], 0, 0, 0);
            acc[1][nt] = __builtin_amdgcn_mfma_f32_16x16x32_f16(a1, bcur[nt], acc[1][nt], 0, 0, 0);
        }
        a0 = a0n; a1 = a1n;
        #pragma unroll
        for (int nt = 0; nt < 4; ++nt) bcur[nt] = bnxt[nt];
    }

    // GEMM1 output -> Bs
    #pragma unroll
    for (int nt = 0; nt < 4; ++nt) {
        int col = cw * 64 + nt * 16 + lm;
        float bv = b1[col];
        #pragma unroll
        for (int mt = 0; mt < 2; ++mt) {
            #pragma unroll
            for (int r = 0; r < 4; ++r) {
                int row = rw * 32 + mt * 16 + quad * 4 + r;
                Bs[row * LDA + col] = (short)f2h(fmaxf(acc[mt][nt][r] + bv, 0.f));
            }
        }
    }
    #pragma unroll
    for (int nt = 0; nt < 4; ++nt)
        bcur[nt] = *(const f16x8*)&Wt2[wrow + nt * 2048];
    __syncthreads();   // b1: Bs ready

    // ---- GEMM 2: acc = Bs @ W2 ----
    #pragma unroll
    for (int mt = 0; mt < 2; ++mt)
        #pragma unroll
        for (int nt = 0; nt < 4; ++nt)
            acc[mt][nt] = (f32x4){0.f, 0.f, 0.f, 0.f};
    #pragma unroll
    for (int ks = 0; ks < 4; ++ks) {
        if (ks < 3) {
            #pragma unroll
            for (int nt = 0; nt < 4; ++nt)
                bnxt[nt] = *(const f16x8*)&Wt2[wrow + nt * 2048 + (ks + 1) * 32];
        }
        int kb = ks * 32 + quad * 8;
        f16x8 c0 = *(const f16x8*)&Bs[(rw * 32 + lm) * LDA + kb];
        f16x8 c1 = *(const f16x8*)&Bs[(rw * 32 + 16 + lm) * LDA + kb];
        #pragma unroll
        for (int nt = 0; nt < 4; ++nt) {
            acc[0][nt] = __builtin_amdgcn_mfma_f32_16x16x32_f16(c0, bcur[nt], acc[0][nt], 0, 0, 0);
            acc[1][nt] = __builtin_amdgcn_mfma_f32_16x16x32_f16(c1, bcur[nt], acc[1][nt], 0, 0, 0);
        }
        #pragma unroll
        for (int nt = 0; nt < 4; ++nt) bcur[nt] = bnxt[nt];
    }
    __syncthreads();   // b2: all Bs reads done, safe to overwrite with Cs

    ushort* Cs = (ushort*)Bs;
    #pragma unroll
    for (int nt = 0; nt < 4; ++nt) {
        int col = cw * 64 + nt * 16 + lm;
        float bv = b2[col];
        #pragma unroll
        for (int mt = 0; mt < 2; ++mt) {
            #pragma unroll
            for (int r = 0; r < 4; ++r) {
                int row = rw * 32 + mt * 16 + quad * 4 + r;
                Cs[row * LDA + col] = (ushort)f2h(fmaxf(acc[mt][nt][r] + bv, 0.f));
            }
        }
    }
    __syncthreads();   // b3: Cs ready

    #pragma unroll
    for (int j = 0; j < 4; ++j) {
        int lin = tid + j * 256;
        int r = lin >> 4;
        int kc = lin & 15;
        int gr = row0 + r;
        if (gr < N_NODES)
            *(uint4*)&C[gr * 128 + kc * 8] = *(const uint4*)&Cs[r * LDA + kc * 8];
    }

    // ---- per-graph + global stats ----
    {
        int c = tid & 127;
        int rbase = (tid >> 7) * 32;
        int curg = sb[rbase];
        float rs = 0.f, rss = 0.f;
        float ts = 0.f, tss = 0.f;
        for (int r = rbase; r < rbase + 32; ++r) {
            int g = sb[r];
            if (g < 0) break;
            if (g != curg) {
                atomicAdd(&gsum[curg * 128 + c], rs);
                atomicAdd(&gssq[curg * 128 + c], rss);
                rs = 0.f; rss = 0.f; curg = g;
            }
            float v = h2f(Cs[r * LDA + c]);
            rs += v; rss += v * v;
            ts += v; tss += v * v;
        }
        if (curg >= 0) {
            atomicAdd(&gsum[curg * 128 + c], rs);
            atomicAdd(&gssq[curg * 128 + c], rss);
        }
        if (tid >= 128) { scr[c] = ts; scr[128 + c] = tss; }
        __syncthreads();   // b4
        if (tid < 128) {
            float* part = bnpart + (blockIdx.x & (NPART - 1)) * 256;
            atomicAdd(&part[c], ts + scr[c]);
            atomicAdd(&part[128 + c], tss + scr[128 + c]);
        }
    }
}

// ---------------- combine (BN affine inline from 16-way partials) ----------------

__global__ __launch_bounds__(256) void combine(const float* __restrict__ gsum,
                                               const float* __restrict__ bnstat,
                                               const int* __restrict__ gcnt,
                                               const float* __restrict__ gamma,
                                               const float* __restrict__ beta,
                                               const float* __restrict__ LW,
                                               const float* __restrict__ LB,
                                               float* __restrict__ out) {
    int gid = blockIdx.x * 256 + threadIdx.x;
    if (gid >= N_GRAPHS * 128) return;
    int g = gid >> 7;
    int d = gid & 127;
    float c = (float)gcnt[g];
    float o = c * LB[0];
    const float invN = 1.0f / (float)N_NODES;
    #pragma unroll
    for (int l = 0; l < N_LAYERS; ++l) {
        const float* part = bnstat + l * NPART * 256;
        float sum = 0.f, ssq = 0.f;
        #pragma unroll
        for (int p = 0; p < NPART; ++p) {
            sum += part[p * 256 + d];
            ssq += part[p * 256 + 128 + d];
        }
        float m = sum * invN;
        float var = ssq * invN - m * m;
        float s = gamma[l * 128 + d] * rsqrtf(var + BN_EPS);
        float t = beta[l * 128 + d] - m * s;
        o += LW[l] * (s * gsum[(l * N_GRAPHS + g) * 128 + d] + c * t);
    }
    out[gid] = o;
}

// ---------------- host launcher ----------------

extern "C" void kernel_launch(void* const* d_in, const int* in_sizes, int n_in,
                              void* d_out, int out_size, void* d_ws, size_t ws_size,
                              hipStream_t stream) {
    const float* x      = (const float*)d_in[0];
    const int*   ei     = (const int*)d_in[1];
    const int*   batch  = (const int*)d_in[2];
    const float* ini_w1 = (const float*)d_in[3];
    const float* ini_b1 = (const float*)d_in[4];
    const float* ini_w2 = (const float*)d_in[5];
    const float* ini_b2 = (const float*)d_in[6];
    const float* gw1    = (const float*)d_in[7];
    const float* gb1    = (const float*)d_in[8];
    const float* gw2    = (const float*)d_in[9];
    const float* gb2    = (const float*)d_in[10];
    const float* gamma  = (const float*)d_in[11];
    const float* beta   = (const float*)d_in[12];
    const float* lw     = (const float*)d_in[13];
    const float* lb     = (const float*)d_in[14];
    float* out = (float*)d_out;

    char* p = (char*)d_ws;
    auto carve = [&](size_t bytes) -> char* {
        char* q = p;
        p += (bytes + 255) & ~(size_t)255;
        return q;
    };
    ushort* z0    = (ushort*)carve(sizeof(ushort) * N_NODES * DIM);
    ushort* z1    = (ushort*)carve(sizeof(ushort) * N_NODES * DIM);
    ushort* abuf  = (ushort*)carve(sizeof(ushort) * N_NODES * DIM);
    float* bnstat = (float*)carve(sizeof(float) * BN_FLOATS);
    float* gsum   = (float*)carve(sizeof(float) * N_LAYERS * N_GRAPHS * DIM);
    float* gssq   = (float*)carve(sizeof(float) * N_LAYERS * N_GRAPHS * DIM);
    short* wbf    = (short*)carve(sizeof(short) * 10 * 128 * 128);
    int* gcnt     = (int*)carve(sizeof(int) * N_GRAPHS);
    int* cnt      = (int*)carve(sizeof(int) * N_NODES);
    ushort* slot  = (ushort*)carve(sizeof(ushort) * N_NODES * SLOT_CAP);

    const int* src = ei;
    const int* dst = ei + N_EDGES;

    hipMemsetAsync(cnt, 0, sizeof(int) * N_NODES, stream);
    hipMemsetAsync(gcnt, 0, sizeof(int) * N_GRAPHS, stream);

    int twblocks = (TW_ELEMS + BN_FLOATS + 255) / 256;
    transpose_weights<<<twblocks, 256, 0, stream>>>(
        ini_w1, ini_w2, gw1, gw2, wbf, bnstat);

    ini_fused<<<GBLOCKS + BG_BLOCKS, 256, 0, stream>>>(
        x, wbf, ini_b1, wbf + 16384, ini_b2, z0,
        src, dst, batch, cnt, slot, gcnt, gsum, gssq);

    ushort* zprev = z0;
    ushort* znext = z1;
    for (int i = 0; i < N_LAYERS; ++i) {
        const float* bp_in = (i == 0) ? nullptr : bnstat + (i - 1) * NPART * 256;
        const float* gptr  = (i == 0) ? gamma : gamma + (i - 1) * DIM;
        const float* bptr  = (i == 0) ? beta : beta + (i - 1) * DIM;
        aggregate_h<<<(N_NODES + 15) / 16, 256, 0, stream>>>(
            zprev, cnt, slot, bp_in, gptr, bptr, abuf);
        gemm_gin<<<GBLOCKS, 256, 0, stream>>>(
            abuf, wbf + (2 + i) * 16384, gb1 + i * DIM,
            wbf + (6 + i) * 16384, gb2 + i * DIM, znext, batch,
            gsum + i * N_GRAPHS * DIM, gssq + i * N_GRAPHS * DIM,
            bnstat + i * NPART * 256);
        ushort* tmp = zprev; zprev = znext; znext = tmp;
    }
    combine<<<(N_GRAPHS * 128 + 255) / 256, 256, 0, stream>>>(
        gsum, bnstat, gcnt, gamma, beta, lw, lb, out);
}